// Round 11
// baseline (1052.719 us; speedup 1.0000x reference)
//
#include <hip/hip_runtime.h>
#include <cstdint>
#include <cstddef>

// ---------------------------------------------------------------------------
// Model dims (fixed): B=64 S=256 E=1024 H=16 D=64 NL=2 FF=4096; T=16384 rows.
// Tier2 (ws >= ~216 MiB): residual h = bf16 in ws. Tier1: h = f32 in d_out.
// ---------------------------------------------------------------------------

typedef __attribute__((ext_vector_type(4))) float f32x4;
typedef __attribute__((ext_vector_type(16))) float f32x16;
typedef __attribute__((ext_vector_type(8))) __bf16 bf16x8;
typedef __attribute__((ext_vector_type(4))) unsigned int u32x4;
typedef __attribute__((ext_vector_type(8))) unsigned short u16x8;
typedef __attribute__((ext_vector_type(4))) unsigned short u16x4;

__device__ __forceinline__ unsigned short f2bf(float x) {
  unsigned int u = __builtin_bit_cast(unsigned int, x);
  u += 0x7fffu + ((u >> 16) & 1u);          // RNE
  return (unsigned short)(u >> 16);
}
__device__ __forceinline__ float b2f(unsigned short x) {
  return __builtin_bit_cast(float, (unsigned int)x << 16);
}
__device__ __forceinline__ float gelu_new(float x) {
  float u = 0.7978845608028654f * (x + 0.044715f * x * x * x);
  return x * __builtin_amdgcn_rcpf(1.0f + __expf(-2.0f * u));
}
__device__ __forceinline__ unsigned int cvtpk(float lo, float hi) {
  unsigned int r;
  asm("v_cvt_pk_bf16_f32 %0, %1, %2" : "=v"(r) : "v"(lo), "v"(hi));
  return r;
}
__device__ __forceinline__ void plswap(unsigned int& a, unsigned int& b) {
  asm("v_permlane32_swap_b32 %0, %1" : "+v"(a), "+v"(b));
}

// sync triplet: pin order, counted wait (NO memory clobber so the waitcnt
// pass does not insert a conservative vmcnt(0)/lgkmcnt(0) drain), raw
// barrier, pin order again (rule #18 pattern).
#define SYNC_VM(N)                                     \
  do {                                                 \
    __builtin_amdgcn_sched_barrier(0);                 \
    asm volatile("s_waitcnt vmcnt(" #N ")");           \
    __builtin_amdgcn_s_barrier();                      \
    __builtin_amdgcn_sched_barrier(0);                 \
  } while (0)

// ---------------------------------------------------------------------------
// Weight convert+transpose: W f32 [K,N] -> Wt bf16 [N,K]
// ---------------------------------------------------------------------------
__global__ __launch_bounds__(256) void transpose_bf16(
    const float* __restrict__ W, unsigned short* __restrict__ Wt, int K, int N) {
  __shared__ float tile[32][33];
  const int n0 = blockIdx.x * 32, k0 = blockIdx.y * 32;
  const int tx = threadIdx.x, ty = threadIdx.y;
#pragma unroll
  for (int j = 0; j < 32; j += 8)
    tile[ty + j][tx] = W[(size_t)(k0 + ty + j) * N + n0 + tx];
  __syncthreads();
#pragma unroll
  for (int j = 0; j < 32; j += 8)
    Wt[(size_t)(n0 + ty + j) * K + k0 + tx] = f2bf(tile[tx][ty + j]);
}

// ---------------------------------------------------------------------------
// LayerNorm, wave-per-row (4 rows / 256-thr block, pure shfl reduce).
// INBF: h input is bf16 (u16x4 groups) or f32 (f32x4 groups).
// OUTF32: 0 -> bf16 out (xb), 1 -> f32 out (final LN into d_out).
// ---------------------------------------------------------------------------
template <int INBF, int OUTF32>
__global__ __launch_bounds__(256) void ln4_kernel(
    const void* __restrict__ hin, const float* __restrict__ g,
    const float* __restrict__ bb, void* __restrict__ outp) {
  const int lane = threadIdx.x & 63;
  const int row = blockIdx.x * 4 + (threadIdx.x >> 6);
  f32x4 v[4];
  if (INBF) {
    const u16x4* src = (const u16x4*)hin + (size_t)row * 256;
#pragma unroll
    for (int j = 0; j < 4; ++j) {
      u16x4 w = src[j * 64 + lane];
      v[j].x = b2f(w.x); v[j].y = b2f(w.y); v[j].z = b2f(w.z); v[j].w = b2f(w.w);
    }
  } else {
    const f32x4* src = (const f32x4*)hin + (size_t)row * 256;
#pragma unroll
    for (int j = 0; j < 4; ++j) v[j] = src[j * 64 + lane];
  }
  float s = 0.f, sq = 0.f;
#pragma unroll
  for (int j = 0; j < 4; ++j) {
    s += v[j].x + v[j].y + v[j].z + v[j].w;
    sq += v[j].x * v[j].x + v[j].y * v[j].y + v[j].z * v[j].z + v[j].w * v[j].w;
  }
#pragma unroll
  for (int off = 32; off; off >>= 1) {
    s += __shfl_xor(s, off, 64);
    sq += __shfl_xor(sq, off, 64);
  }
  const float mean = s * (1.0f / 1024.0f);
  const float var = sq * (1.0f / 1024.0f) - mean * mean;
  const float rs = rsqrtf(var + 1e-5f);
#pragma unroll
  for (int j = 0; j < 4; ++j) {
    const f32x4 gv = ((const f32x4*)g)[j * 64 + lane];
    const f32x4 bv = ((const f32x4*)bb)[j * 64 + lane];
    float y0 = (v[j].x - mean) * rs * gv.x + bv.x;
    float y1 = (v[j].y - mean) * rs * gv.y + bv.y;
    float y2 = (v[j].z - mean) * rs * gv.z + bv.z;
    float y3 = (v[j].w - mean) * rs * gv.w + bv.w;
    if (OUTF32) {
      f32x4 o; o.x = y0; o.y = y1; o.z = y2; o.w = y3;
      ((f32x4*)outp)[(size_t)row * 256 + j * 64 + lane] = o;
    } else {
      u16x4 pk;
      pk.x = f2bf(y0); pk.y = f2bf(y1); pk.z = f2bf(y2); pk.w = f2bf(y3);
      ((u16x4*)outp)[(size_t)row * 256 + j * 64 + lane] = pk;
    }
  }
}

// fused: h = sent + wpe[s] (stored f32 or bf16 per HBF);  xb = LN(h)
template <int HBF>
__global__ __launch_bounds__(256) void ln4_wpe_kernel(
    const float* __restrict__ sent, const float* __restrict__ wpe,
    const float* __restrict__ g, const float* __restrict__ bb,
    void* __restrict__ h, unsigned short* __restrict__ xb) {
  const int lane = threadIdx.x & 63;
  const int row = blockIdx.x * 4 + (threadIdx.x >> 6);
  const int sp = row & 255;
  const f32x4* src = (const f32x4*)(sent + (size_t)row * 1024);
  const f32x4* wp = (const f32x4*)(wpe + (size_t)sp * 1024);
  f32x4 v[4];
#pragma unroll
  for (int j = 0; j < 4; ++j) {
    v[j] = src[j * 64 + lane] + wp[j * 64 + lane];
    if (HBF) {
      u16x4 pk;
      pk.x = f2bf(v[j].x); pk.y = f2bf(v[j].y);
      pk.z = f2bf(v[j].z); pk.w = f2bf(v[j].w);
      ((u16x4*)h)[(size_t)row * 256 + j * 64 + lane] = pk;
      v[j].x = b2f(pk.x); v[j].y = b2f(pk.y); v[j].z = b2f(pk.z); v[j].w = b2f(pk.w);
    } else {
      ((f32x4*)h)[(size_t)row * 256 + j * 64 + lane] = v[j];
    }
  }
  float s = 0.f, sq = 0.f;
#pragma unroll
  for (int j = 0; j < 4; ++j) {
    s += v[j].x + v[j].y + v[j].z + v[j].w;
    sq += v[j].x * v[j].x + v[j].y * v[j].y + v[j].z * v[j].z + v[j].w * v[j].w;
  }
#pragma unroll
  for (int off = 32; off; off >>= 1) {
    s += __shfl_xor(s, off, 64);
    sq += __shfl_xor(sq, off, 64);
  }
  const float mean = s * (1.0f / 1024.0f);
  const float var = sq * (1.0f / 1024.0f) - mean * mean;
  const float rs = rsqrtf(var + 1e-5f);
#pragma unroll
  for (int j = 0; j < 4; ++j) {
    const f32x4 gv = ((const f32x4*)g)[j * 64 + lane];
    const f32x4 bv = ((const f32x4*)bb)[j * 64 + lane];
    u16x4 pk;
    pk.x = f2bf((v[j].x - mean) * rs * gv.x + bv.x);
    pk.y = f2bf((v[j].y - mean) * rs * gv.y + bv.y);
    pk.z = f2bf((v[j].z - mean) * rs * gv.z + bv.z);
    pk.w = f2bf((v[j].w - mean) * rs * gv.w + bv.w);
    ((u16x4*)xb)[(size_t)row * 256 + j * 64 + lane] = pk;
  }
}

// ---------------------------------------------------------------------------
// gemmp: 256x256 tile, BK=64, 8 waves (2m x 4n), register-pipelined schedule,
// two counted {sched_barrier|vmcnt(N)|s_barrier|sched_barrier} per K-tile
// (clobber-free waits so the compiler cannot re-insert full drains), setprio,
// XOR chunk^row LDS swizzle (0 conflicts), XCD 4x4 block chunks.
// EPI: 0 = bf16 (+bias), 1 = bf16 gelu(+bias), 2 = residual +=
// HBF (EPI=2 only): 0 -> f32 h scatter, 1 -> bf16 h coalesced LDS-repack RMW
// ---------------------------------------------------------------------------
template <int EPI, int HBF>
__global__ __launch_bounds__(512, 2) void gemmp(
    const unsigned short* __restrict__ A, const unsigned short* __restrict__ Bt,
    const float* __restrict__ bias, unsigned short* __restrict__ Cb,
    void* __restrict__ Hres, int N, int K, int gx, int gy) {
  constexpr int A_E = 16384;               // 256x64 A elems
  constexpr int BUF_E = A_E + 16384;       // + B 256x64
  __shared__ alignas(16) unsigned short smem[2 * BUF_E];

  // ---- block swizzle: XCD contiguous range; 4x4 chunks, bx fastest ----
  const int nwg = gx * gy;
  const int dd = blockIdx.x;
  const int wrk = (dd & 7) * (nwg >> 3) + (dd >> 3);
  const int cid = wrk >> 4;
  const int cin = wrk & 15;
  const int cpr = gx >> 2;
  const int cby = cid / cpr;
  const int cbx = cid - cby * cpr;
  const int bx = cbx * 4 + (cin & 3);
  const int by = cby * 4 + (cin >> 2);
  const int row0 = by * 256, col0 = bx * 256;

  const int t = threadIdx.x;
  const int wid = t >> 6, l = t & 63;
  const int wm = wid >> 2, wn = wid & 3;
  const int fr = l & 15, q4 = l >> 4;

  const int cx0 = (q4 ^ (fr & 7)) * 8;
  const int cx1 = ((4 + q4) ^ (fr & 7)) * 8;
  const int b_r0 = (wn * 64 + fr) * 64;
  auto a_slot = [&](int m) -> int { return (wm * 128 + m * 16 + fr) * 64; };

  const int lrow = l >> 3;
  const int scol = ((l & 7) ^ (lrow & 7)) * 8;

  auto stB = [&](int tt, int win) {
    const unsigned short* s =
        Bt + (size_t)(col0 + win * 8 + lrow) * K + tt * 64 + scol;
    __builtin_amdgcn_global_load_lds(
        (const __attribute__((address_space(1))) void*)s,
        (__attribute__((address_space(3))) void*)(smem + (tt & 1) * BUF_E + A_E + win * 512),
        16, 0, 0);
  };
  auto stA = [&](int tt, int win) {
    const unsigned short* s =
        A + (size_t)(row0 + win * 8 + lrow) * K + tt * 64 + scol;
    __builtin_amdgcn_global_load_lds(
        (const __attribute__((address_space(1))) void*)s,
        (__attribute__((address_space(3))) void*)(smem + (tt & 1) * BUF_E + win * 512),
        16, 0, 0);
  };
  auto stageB_set = [&](int tt) {
    stB(tt, 2 * wid); stB(tt, 2 * wid + 1);
    stB(tt, 16 + 2 * wid); stB(tt, 16 + 2 * wid + 1);
  };
  auto stageA_set = [&](int tt) {   // early pair (m0-3 rows) then late pair
    const int i0 = 2 * wid, i1 = 2 * wid + 1;
    stA(tt, i0 < 8 ? i0 : 8 + i0);
    stA(tt, i1 < 8 ? i1 : 8 + i1);
    stA(tt, i0 < 8 ? 8 + i0 : 16 + i0);
    stA(tt, i1 < 8 ? 8 + i1 : 16 + i1);
  };

  const int nt = K >> 6;

  stageB_set(0);
  stageA_set(0);
  SYNC_VM(2);          // leave A-late(0) (2 newest) in flight

  f32x4 acc[8][4];
#pragma unroll
  for (int m = 0; m < 8; ++m)
#pragma unroll
    for (int n = 0; n < 4; ++n) {
      acc[m][n].x = 0.f; acc[m][n].y = 0.f; acc[m][n].z = 0.f; acc[m][n].w = 0.f;
    }

  for (int tc = 0; tc < nt; ++tc) {
    const unsigned short* Ab = smem + (tc & 1) * BUF_E;
    const unsigned short* Bb = Ab + A_E;
    const bool pf = (tc + 1) < nt;

    bf16x8 b0[4], b1[4], a0[4], a1[4];
#pragma unroll
    for (int n = 0; n < 4; ++n) b0[n] = *(const bf16x8*)(Bb + b_r0 + n * 1024 + cx0);
#pragma unroll
    for (int m = 0; m < 4; ++m) a0[m] = *(const bf16x8*)(Ab + a_slot(m) + cx0);
#pragma unroll
    for (int n = 0; n < 4; ++n) b1[n] = *(const bf16x8*)(Bb + b_r0 + n * 1024 + cx1);
#pragma unroll
    for (int m = 0; m < 4; ++m) a1[m] = *(const bf16x8*)(Ab + a_slot(m) + cx1);

    if (pf) stageB_set(tc + 1);

    __builtin_amdgcn_s_setprio(1);
#pragma unroll
    for (int m = 0; m < 4; ++m)
#pragma unroll
      for (int n = 0; n < 4; ++n)
        acc[m][n] = __builtin_amdgcn_mfma_f32_16x16x32_bf16(a0[m], b0[n], acc[m][n], 0, 0, 0);
    __builtin_amdgcn_s_setprio(0);

    if (pf) stageA_set(tc + 1);

    __builtin_amdgcn_s_setprio(1);
#pragma unroll
    for (int m = 0; m < 4; ++m)
#pragma unroll
      for (int n = 0; n < 4; ++n)
        acc[m][n] = __builtin_amdgcn_mfma_f32_16x16x32_bf16(a1[m], b1[n], acc[m][n], 0, 0, 0);
    __builtin_amdgcn_s_setprio(0);

    // mid: force A-late(tc) landed; leave B+A(tc+1) (8) in flight
    if (pf) SYNC_VM(8);
    else    SYNC_VM(0);

    bf16x8 h0[4], h1[4];
#pragma unroll
    for (int m = 0; m < 4; ++m) h0[m] = *(const bf16x8*)(Ab + a_slot(4 + m) + cx0);
#pragma unroll
    for (int m = 0; m < 4; ++m) h1[m] = *(const bf16x8*)(Ab + a_slot(4 + m) + cx1);

    __builtin_amdgcn_s_setprio(1);
#pragma unroll
    for (int m = 0; m < 4; ++m)
#pragma unroll
      for (int n = 0; n < 4; ++n)
        acc[4 + m][n] = __builtin_amdgcn_mfma_f32_16x16x32_bf16(h0[m], b0[n], acc[4 + m][n], 0, 0, 0);
    __builtin_amdgcn_s_setprio(0);
    __builtin_amdgcn_s_setprio(1);
#pragma unroll
    for (int m = 0; m < 4; ++m)
#pragma unroll
      for (int n = 0; n < 4; ++n)
        acc[4 + m][n] = __builtin_amdgcn_mfma_f32_16x16x32_bf16(h1[m], b1[n], acc[4 + m][n], 0, 0, 0);
    __builtin_amdgcn_s_setprio(0);

    // boundary: force B+A-early(tc+1); leave A-late(tc+1) in flight
    if (pf) SYNC_VM(2);
    else    SYNC_VM(0);
  }

  // ---- epilogue ----
  if constexpr (EPI == 2 && HBF == 0) {
    float* Hf = (float*)Hres;
#pragma unroll
    for (int n = 0; n < 4; ++n) {
      const int col = col0 + wn * 64 + n * 16 + fr;
      const float bi = bias[col];
#pragma unroll
      for (int m = 0; m < 8; ++m)
#pragma unroll
        for (int e = 0; e < 4; ++e) {
          const int row = row0 + wm * 128 + m * 16 + q4 * 4 + e;
          Hf[(size_t)row * N + col] += acc[m][n][e] + bi;
        }
    }
  } else {
    unsigned short* Hb = (unsigned short*)Hres;
    char* wreg = (char*)smem + wid * 9216;
    float bi[4];
#pragma unroll
    for (int n = 0; n < 4; ++n) bi[n] = bias[col0 + wn * 64 + n * 16 + fr];
#pragma unroll
    for (int half = 0; half < 2; ++half) {
#pragma unroll
      for (int m = 0; m < 4; ++m)
#pragma unroll
        for (int n = 0; n < 4; ++n)
#pragma unroll
          for (int e = 0; e < 4; ++e) {
            float v = acc[half * 4 + m][n][e] + bi[n];
            if (EPI == 1) v = gelu_new(v);
            *(unsigned short*)(wreg + (m * 16 + q4 * 4 + e) * 144 +
                               (n * 16 + fr) * 2) = f2bf(v);
          }
#pragma unroll
      for (int rb = 0; rb < 8; ++rb) {
        const int rowl = rb * 8 + (l >> 3);
        u16x8 vv = *(const u16x8*)(wreg + rowl * 144 + (l & 7) * 16);
        const int rg = row0 + wm * 128 + half * 64 + rowl;
        unsigned short* dst =
            (EPI == 2 ? Hb : Cb) + (size_t)rg * N + col0 + wn * 64 + (l & 7) * 8;
        if (EPI == 2) {
          u16x8 hv = *(const u16x8*)dst;
          u16x8 o;
#pragma unroll
          for (int e = 0; e < 8; ++e) o[e] = f2bf(b2f(hv[e]) + b2f(vv[e]));
          *(u16x8*)dst = o;
        } else {
          *(u16x8*)dst = vv;
        }
      }
    }
  }
}

// ---------------------------------------------------------------------------
// MFMA flash attention (unchanged; verified rounds 3-10).
// ---------------------------------------------------------------------------
__global__ __launch_bounds__(256) void attn_mfma(
    const unsigned short* __restrict__ qkv, unsigned short* __restrict__ aout,
    int b0) {
  __shared__ alignas(16) unsigned short Klds[256 * 64];
  __shared__ alignas(16) unsigned short Vt[64 * 256];
  const int bh = blockIdx.x;
  const int bl = bh >> 4, hd = bh & 15;
  const size_t base = (size_t)bl * 256 * 3072 + (size_t)hd * 64;
  const int t = threadIdx.x;
  const int w = t >> 6, l = t & 63;
  const int lq = l & 31, hl = l >> 5;

#pragma unroll
  for (int i = 0; i < 8; ++i) {
    const int r = i * 32 + (t >> 3);
    const int c = t & 7;
    u16x8 kv = *(const u16x8*)(qkv + base + (size_t)r * 3072 + 1024 + c * 8);
    *(u16x8*)(Klds + r * 64 + ((c ^ (r & 7)) * 8)) = kv;
    u16x8 vv = *(const u16x8*)(qkv + base + (size_t)r * 3072 + 2048 + c * 8);
#pragma unroll
    for (int j = 0; j < 8; ++j) {
      const int d = c * 8 + j;
      Vt[d * 256 + (((r >> 3) ^ (d & 31)) * 8) + (r & 7)] = vv[j];
    }
  }

  const int q0 = w * 64;
  bf16x8 qf[2][4];
#pragma unroll
  for (int n = 0; n < 2; ++n)
#pragma unroll
    for (int d16 = 0; d16 < 4; ++d16)
      qf[n][d16] = *(const bf16x8*)(qkv + base +
          (size_t)(q0 + n * 32 + lq) * 3072 + d16 * 16 + hl * 8);
  __syncthreads();

  const float cs = 0.125f * 1.44269504088896f;
  f32x16 O[2][2];
#pragma unroll
  for (int m = 0; m < 2; ++m)
#pragma unroll
    for (int n = 0; n < 2; ++n)
#pragma unroll
      for (int e = 0; e < 16; ++e) O[m][n][e] = 0.f;
  float mrun[2] = {-3.0e38f, -3.0e38f};
  float lrun[2] = {0.f, 0.f};

  const int ktmax = (q0 + 63) >> 5;
  for (int kt = 0; kt <= ktmax; ++kt) {
    bf16x8 kf[4];
    const int krow = kt * 32 + lq;
#pragma unroll
    for (int d16 = 0; d16 < 4; ++d16) {
      const int chunk = (d16 * 2 + hl) ^ (krow & 7);
      kf[d16] = *(const bf16x8*)(Klds + krow * 64 + chunk * 8);
    }
    const int nlo = (kt * 32 > q0 + 31) ? 1 : 0;
    bf16x8 pfrag[2][2];
#pragma unroll
    for (int n = 0; n < 2; ++n) {
      if (n < nlo) continue;
      f32x16 s;
#pragma unroll
      for (int e = 0; e < 16; ++e) s[e] = 0.f;
#pragma unroll
      for (int d16 = 0; d16 < 4; ++d16)
        s = __builtin_amdgcn_mfma_f32_32x32x16_bf16(kf[d16], qf[n][d16], s, 0, 0, 0);
      const int qg = q0 + n * 32 + lq;
      float sv[16];
#pragma unroll
      for (int r = 0; r < 16; ++r) {
        const int kg = kt * 32 + (r & 3) + 8 * (r >> 2) + 4 * hl;
        const float x = s[r] * cs;
        sv[r] = (kg > qg) ? -3.0e38f : x;
      }
      float pmax = sv[0];
#pragma unroll
      for (int r = 1; r < 16; ++r) pmax = fmaxf(pmax, sv[r]);
      pmax = fmaxf(pmax, __shfl_xor(pmax, 32, 64));
      const float nm = fmaxf(mrun[n], pmax);
      const float alpha = exp2f(mrun[n] - nm);
      mrun[n] = nm;
      float psum = 0.f;
#pragma unroll
      for (int r = 0; r < 16; ++r) {
        sv[r] = exp2f(sv[r] - nm);
        psum += sv[r];
      }
      psum += __shfl_xor(psum, 32, 64);
      lrun[n] = lrun[n] * alpha + psum;
#pragma unroll
      for (int m = 0; m < 2; ++m)
#pragma unroll
        for (int e = 0; e < 16; ++e) O[m][n][e] *= alpha;
#pragma unroll
      for (int h = 0; h < 2; ++h) {
        unsigned int a0 = cvtpk(sv[h * 8 + 0], sv[h * 8 + 1]);
        unsigned int a1 = cvtpk(sv[h * 8 + 2], sv[h * 8 + 3]);
        unsigned int c0 = cvtpk(sv[h * 8 + 4], sv[h * 8 + 5]);
        unsigned int c1 = cvtpk(sv[h * 8 + 6], sv[h * 8 + 7]);
        plswap(a0, c0);
        plswap(a1, c1);
        u32x4 fw; fw.x = a0; fw.y = a1; fw.z = c0; fw.w = c1;
        pfrag[n][h] = __builtin_bit_cast(bf16x8, fw);
      }
    }
#pragma unroll
    for (int m = 0; m < 2; ++m)
#pragma unroll
      for (int h = 0; h < 2; ++h) {
        const int dd = m * 32 + lq;
        const int chunk = (kt * 4 + h * 2 + hl) ^ (dd & 31);
        bf16x8 vf = *(const bf16x8*)(Vt + dd * 256 + chunk * 8);
#pragma unroll
        for (int n = 0; n < 2; ++n)
          if (n >= nlo)
            O[m][n] = __builtin_amdgcn_mfma_f32_32x32x16_bf16(vf, pfrag[n][h], O[m][n], 0, 0, 0);
      }
  }

#pragma unroll
  for (int n = 0; n < 2; ++n) {
    const float inv = 1.0f / lrun[n];
    const size_t row = (size_t)(b0 + bl) * 256 + q0 + n * 32 + lq;
#pragma unroll
    for (int m = 0; m < 2; ++m) {
#pragma unroll
      for (int qd = 0; qd < 4; ++qd) {
        u16x4 pk;
#pragma unroll
        for (int e = 0; e < 4; ++e) pk[e] = f2bf(O[m][n][qd * 4 + e] * inv);
        *(u16x4*)(aout + row * 1024 + hd * 64 + m * 32 + qd * 8 + hl * 4) = pk;
      }
    }
  }
}

// ---------------------------------------------------------------------------
// Loss
// ---------------------------------------------------------------------------
__device__ __forceinline__ float block_reduce_sum256(float v) {
#pragma unroll
  for (int off = 32; off; off >>= 1) v += __shfl_xor(v, off, 64);
  __shared__ float red[4];
  const int t = threadIdx.x;
  if ((t & 63) == 0) red[t >> 6] = v;
  __syncthreads();
  return red[0] + red[1] + red[2] + red[3];
}

__global__ __launch_bounds__(256) void loss_partial(
    const float* __restrict__ hf, const float* __restrict__ sent,
    float* __restrict__ part) {
  const int s = blockIdx.x, t = threadIdx.x;
  f32x4 a = ((const f32x4*)(hf + (size_t)s * 1024))[t];
  f32x4 b = ((const f32x4*)(sent + (size_t)(s + 1) * 1024))[t];
  f32x4 d = a - b;
  float v = d.x * d.x + d.y * d.y + d.z * d.z + d.w * d.w;
  float tot = block_reduce_sum256(v);
  if (t == 0) part[s] = tot;
}

__global__ __launch_bounds__(256) void loss_final(
    const float* __restrict__ part, float* __restrict__ out) {
  const int t = threadIdx.x;
  float v = (t < 255) ? part[t] : 0.f;
  float s = block_reduce_sum256(v);
  if (t == 0) out[0] = s * (1.0f / (255.0f * 1024.0f));
}

// ---------------------------------------------------------------------------
// Workspace layouts (identical to round 10)
// ---------------------------------------------------------------------------
constexpr size_t F_X     = 0;
constexpr size_t F_U     = 33554432;
constexpr size_t F_WQKV  = F_U + 134217728;
constexpr size_t F_WPROJ = F_WQKV + 6291456;
constexpr size_t F_WFC   = F_WPROJ + 2097152;
constexpr size_t F_WMLP  = F_WFC + 8388608;
constexpr size_t F_PART  = F_WMLP + 8388608;

constexpr size_t G_X     = 0;
constexpr size_t G_H     = 33554432;
constexpr size_t G_U     = G_H + 33554432;
constexpr size_t G_WQKV  = G_U + 134217728;
constexpr size_t G_WPROJ = G_WQKV + 6291456;
constexpr size_t G_WFC   = G_WPROJ + 2097152;
constexpr size_t G_WMLP  = G_WFC + 8388608;
constexpr size_t G_PART  = G_WMLP + 8388608;
constexpr size_t G_NEED  = G_PART + 4096;

extern "C" void kernel_launch(void* const* d_in, const int* in_sizes, int n_in,
                              void* d_out, int out_size, void* d_ws, size_t ws_size,
                              hipStream_t stream) {
  (void)in_sizes; (void)n_in; (void)out_size;
  const float* sent    = (const float*)d_in[0];
  const float* wpe     = (const float*)d_in[1];
  const float* ln1_g   = (const float*)d_in[2];
  const float* ln1_b   = (const float*)d_in[3];
  const float* attn_w  = (const float*)d_in[4];
  const float* attn_b  = (const float*)d_in[5];
  const float* attn_pw = (const float*)d_in[6];
  const float* attn_pb = (const float*)d_in[7];
  const float* ln2_g   = (const float*)d_in[8];
  const float* ln2_b   = (const float*)d_in[9];
  const float* fc_w    = (const float*)d_in[10];
  const float* fc_b    = (const float*)d_in[11];
  const float* mlp_w   = (const float*)d_in[12];
  const float* mlp_b   = (const float*)d_in[13];
  const float* lnf_g   = (const float*)d_in[14];
  const float* lnf_b   = (const float*)d_in[15];
  float* out_h = (float*)d_out;

  char* ws = (char*)d_ws;
  const bool t2 = ws_size >= G_NEED;

  unsigned short* xb    = (unsigned short*)(ws + (t2 ? G_X : F_X));
  unsigned short* hb    = (unsigned short*)(ws + G_H);
  unsigned short* ub    = (unsigned short*)(ws + (t2 ? G_U : F_U));
  unsigned short* wqkv  = (unsigned short*)(ws + (t2 ? G_WQKV : F_WQKV));
  unsigned short* wproj = (unsigned short*)(ws + (t2 ? G_WPROJ : F_WPROJ));
  unsigned short* wfc   = (unsigned short*)(ws + (t2 ? G_WFC : F_WFC));
  unsigned short* wmlp  = (unsigned short*)(ws + (t2 ? G_WMLP : F_WMLP));
  float* part           = (float*)(ws + (t2 ? G_PART : F_PART));

  void* h = t2 ? (void*)hb : (void*)out_h;

  const dim3 tb(32, 8, 1);
  for (int i = 0; i < 2; ++i) {
    transpose_bf16<<<dim3(96, 32), tb, 0, stream>>>(
        attn_w + (size_t)i * 1024 * 3072, wqkv, 1024, 3072);
    transpose_bf16<<<dim3(32, 32), tb, 0, stream>>>(
        attn_pw + (size_t)i * 1024 * 1024, wproj, 1024, 1024);
    transpose_bf16<<<dim3(128, 32), tb, 0, stream>>>(
        fc_w + (size_t)i * 1024 * 4096, wfc, 1024, 4096);
    transpose_bf16<<<dim3(32, 128), tb, 0, stream>>>(
        mlp_w + (size_t)i * 4096 * 1024, wmlp, 4096, 1024);

    // --- attention block ---
    if (i == 0) {
      if (t2) ln4_wpe_kernel<1><<<4096, 256, 0, stream>>>(sent, wpe, ln1_g, ln1_b, h, xb);
      else    ln4_wpe_kernel<0><<<4096, 256, 0, stream>>>(sent, wpe, ln1_g, ln1_b, h, xb);
    } else {
      if (t2) ln4_kernel<1, 0><<<4096, 256, 0, stream>>>(h, ln1_g + i * 1024, ln1_b + i * 1024, xb);
      else    ln4_kernel<0, 0><<<4096, 256, 0, stream>>>(h, ln1_g + i * 1024, ln1_b + i * 1024, xb);
    }

    gemmp<0, 0><<<768, 512, 0, stream>>>(
        xb, wqkv, attn_b + i * 3072, ub, nullptr, 3072, 1024, 12, 64);
    attn_mfma<<<1024, 256, 0, stream>>>(ub, xb, 0);

    if (t2)
      gemmp<2, 1><<<256, 512, 0, stream>>>(
          xb, wproj, attn_pb + i * 1024, nullptr, h, 1024, 1024, 4, 64);
    else
      gemmp<2, 0><<<256, 512, 0, stream>>>(
          xb, wproj, attn_pb + i * 1024, nullptr, h, 1024, 1024, 4, 64);

    // --- MLP block ---
    if (t2) ln4_kernel<1, 0><<<4096, 256, 0, stream>>>(h, ln2_g + i * 1024, ln2_b + i * 1024, xb);
    else    ln4_kernel<0, 0><<<4096, 256, 0, stream>>>(h, ln2_g + i * 1024, ln2_b + i * 1024, xb);

    gemmp<1, 0><<<1024, 512, 0, stream>>>(
        xb, wfc, fc_b + i * 4096, ub, nullptr, 4096, 1024, 16, 64);

    if (t2)
      gemmp<2, 1><<<256, 512, 0, stream>>>(
          ub, wmlp, mlp_b + i * 1024, nullptr, h, 1024, 4096, 4, 64);
    else
      gemmp<2, 0><<<256, 512, 0, stream>>>(
          ub, wmlp, mlp_b + i * 1024, nullptr, h, 1024, 4096, 4, 64);
  }

  if (t2) ln4_kernel<1, 1><<<4096, 256, 0, stream>>>(h, lnf_g, lnf_b, out_h);
  else    ln4_kernel<0, 1><<<4096, 256, 0, stream>>>(h, lnf_g, lnf_b, out_h);
  loss_partial<<<255, 256, 0, stream>>>(out_h, sent, part);
  loss_final<<<1, 256, 0, stream>>>(part, out_h + 16777216);
}

// Round 12
// 1037.680 us; speedup vs baseline: 1.0145x; 1.0145x over previous
//
#include <hip/hip_runtime.h>
#include <cstdint>
#include <cstddef>

// ---------------------------------------------------------------------------
// Model dims (fixed): B=64 S=256 E=1024 H=16 D=64 NL=2 FF=4096; T=16384 rows.
// Tier2 (ws >= ~216 MiB): residual h = bf16 in ws. Tier1: h = f32 in d_out.
// ---------------------------------------------------------------------------

typedef __attribute__((ext_vector_type(4))) float f32x4;
typedef __attribute__((ext_vector_type(16))) float f32x16;
typedef __attribute__((ext_vector_type(8))) __bf16 bf16x8;
typedef __attribute__((ext_vector_type(4))) unsigned int u32x4;
typedef __attribute__((ext_vector_type(8))) unsigned short u16x8;
typedef __attribute__((ext_vector_type(4))) unsigned short u16x4;

__device__ __forceinline__ unsigned short f2bf(float x) {
  unsigned int u = __builtin_bit_cast(unsigned int, x);
  u += 0x7fffu + ((u >> 16) & 1u);          // RNE
  return (unsigned short)(u >> 16);
}
__device__ __forceinline__ float b2f(unsigned short x) {
  return __builtin_bit_cast(float, (unsigned int)x << 16);
}
__device__ __forceinline__ float gelu_new(float x) {
  float u = 0.7978845608028654f * (x + 0.044715f * x * x * x);
  return x * __builtin_amdgcn_rcpf(1.0f + __expf(-2.0f * u));
}
__device__ __forceinline__ unsigned int cvtpk(float lo, float hi) {
  unsigned int r;
  asm("v_cvt_pk_bf16_f32 %0, %1, %2" : "=v"(r) : "v"(lo), "v"(hi));
  return r;
}
__device__ __forceinline__ void plswap(unsigned int& a, unsigned int& b) {
  asm("v_permlane32_swap_b32 %0, %1" : "+v"(a), "+v"(b));
}

// boundary sync: pin order, full wait (loads were issued a whole K-tile ago,
// so the drain is ~free), raw barrier, pin order again.
#define SYNC_TILE()                                    \
  do {                                                 \
    __builtin_amdgcn_sched_barrier(0);                 \
    asm volatile("s_waitcnt vmcnt(0)");                \
    __builtin_amdgcn_s_barrier();                      \
    __builtin_amdgcn_sched_barrier(0);                 \
  } while (0)

// ---------------------------------------------------------------------------
// Weight convert+transpose: W f32 [K,N] -> Wt bf16 [N,K]
// ---------------------------------------------------------------------------
__global__ __launch_bounds__(256) void transpose_bf16(
    const float* __restrict__ W, unsigned short* __restrict__ Wt, int K, int N) {
  __shared__ float tile[32][33];
  const int n0 = blockIdx.x * 32, k0 = blockIdx.y * 32;
  const int tx = threadIdx.x, ty = threadIdx.y;
#pragma unroll
  for (int j = 0; j < 32; j += 8)
    tile[ty + j][tx] = W[(size_t)(k0 + ty + j) * N + n0 + tx];
  __syncthreads();
#pragma unroll
  for (int j = 0; j < 32; j += 8)
    Wt[(size_t)(n0 + ty + j) * K + k0 + tx] = f2bf(tile[tx][ty + j]);
}

// ---------------------------------------------------------------------------
// LayerNorm, wave-per-row (4 rows / 256-thr block, pure shfl reduce).
// ---------------------------------------------------------------------------
template <int INBF, int OUTF32>
__global__ __launch_bounds__(256) void ln4_kernel(
    const void* __restrict__ hin, const float* __restrict__ g,
    const float* __restrict__ bb, void* __restrict__ outp) {
  const int lane = threadIdx.x & 63;
  const int row = blockIdx.x * 4 + (threadIdx.x >> 6);
  f32x4 v[4];
  if (INBF) {
    const u16x4* src = (const u16x4*)hin + (size_t)row * 256;
#pragma unroll
    for (int j = 0; j < 4; ++j) {
      u16x4 w = src[j * 64 + lane];
      v[j].x = b2f(w.x); v[j].y = b2f(w.y); v[j].z = b2f(w.z); v[j].w = b2f(w.w);
    }
  } else {
    const f32x4* src = (const f32x4*)hin + (size_t)row * 256;
#pragma unroll
    for (int j = 0; j < 4; ++j) v[j] = src[j * 64 + lane];
  }
  float s = 0.f, sq = 0.f;
#pragma unroll
  for (int j = 0; j < 4; ++j) {
    s += v[j].x + v[j].y + v[j].z + v[j].w;
    sq += v[j].x * v[j].x + v[j].y * v[j].y + v[j].z * v[j].z + v[j].w * v[j].w;
  }
#pragma unroll
  for (int off = 32; off; off >>= 1) {
    s += __shfl_xor(s, off, 64);
    sq += __shfl_xor(sq, off, 64);
  }
  const float mean = s * (1.0f / 1024.0f);
  const float var = sq * (1.0f / 1024.0f) - mean * mean;
  const float rs = rsqrtf(var + 1e-5f);
#pragma unroll
  for (int j = 0; j < 4; ++j) {
    const f32x4 gv = ((const f32x4*)g)[j * 64 + lane];
    const f32x4 bv = ((const f32x4*)bb)[j * 64 + lane];
    float y0 = (v[j].x - mean) * rs * gv.x + bv.x;
    float y1 = (v[j].y - mean) * rs * gv.y + bv.y;
    float y2 = (v[j].z - mean) * rs * gv.z + bv.z;
    float y3 = (v[j].w - mean) * rs * gv.w + bv.w;
    if (OUTF32) {
      f32x4 o; o.x = y0; o.y = y1; o.z = y2; o.w = y3;
      ((f32x4*)outp)[(size_t)row * 256 + j * 64 + lane] = o;
    } else {
      u16x4 pk;
      pk.x = f2bf(y0); pk.y = f2bf(y1); pk.z = f2bf(y2); pk.w = f2bf(y3);
      ((u16x4*)outp)[(size_t)row * 256 + j * 64 + lane] = pk;
    }
  }
}

// fused: h = sent + wpe[s] (stored f32 or bf16 per HBF);  xb = LN(h)
template <int HBF>
__global__ __launch_bounds__(256) void ln4_wpe_kernel(
    const float* __restrict__ sent, const float* __restrict__ wpe,
    const float* __restrict__ g, const float* __restrict__ bb,
    void* __restrict__ h, unsigned short* __restrict__ xb) {
  const int lane = threadIdx.x & 63;
  const int row = blockIdx.x * 4 + (threadIdx.x >> 6);
  const int sp = row & 255;
  const f32x4* src = (const f32x4*)(sent + (size_t)row * 1024);
  const f32x4* wp = (const f32x4*)(wpe + (size_t)sp * 1024);
  f32x4 v[4];
#pragma unroll
  for (int j = 0; j < 4; ++j) {
    v[j] = src[j * 64 + lane] + wp[j * 64 + lane];
    if (HBF) {
      u16x4 pk;
      pk.x = f2bf(v[j].x); pk.y = f2bf(v[j].y);
      pk.z = f2bf(v[j].z); pk.w = f2bf(v[j].w);
      ((u16x4*)h)[(size_t)row * 256 + j * 64 + lane] = pk;
      v[j].x = b2f(pk.x); v[j].y = b2f(pk.y); v[j].z = b2f(pk.z); v[j].w = b2f(pk.w);
    } else {
      ((f32x4*)h)[(size_t)row * 256 + j * 64 + lane] = v[j];
    }
  }
  float s = 0.f, sq = 0.f;
#pragma unroll
  for (int j = 0; j < 4; ++j) {
    s += v[j].x + v[j].y + v[j].z + v[j].w;
    sq += v[j].x * v[j].x + v[j].y * v[j].y + v[j].z * v[j].z + v[j].w * v[j].w;
  }
#pragma unroll
  for (int off = 32; off; off >>= 1) {
    s += __shfl_xor(s, off, 64);
    sq += __shfl_xor(sq, off, 64);
  }
  const float mean = s * (1.0f / 1024.0f);
  const float var = sq * (1.0f / 1024.0f) - mean * mean;
  const float rs = rsqrtf(var + 1e-5f);
#pragma unroll
  for (int j = 0; j < 4; ++j) {
    const f32x4 gv = ((const f32x4*)g)[j * 64 + lane];
    const f32x4 bv = ((const f32x4*)bb)[j * 64 + lane];
    u16x4 pk;
    pk.x = f2bf((v[j].x - mean) * rs * gv.x + bv.x);
    pk.y = f2bf((v[j].y - mean) * rs * gv.y + bv.y);
    pk.z = f2bf((v[j].z - mean) * rs * gv.z + bv.z);
    pk.w = f2bf((v[j].w - mean) * rs * gv.w + bv.w);
    ((u16x4*)xb)[(size_t)row * 256 + j * 64 + lane] = pk;
  }
}

// ---------------------------------------------------------------------------
// gemmp: 256x256 tile, BK=64, 8 waves (2m x 4n). MINIMAL-SYNC schedule:
//   tile top: 16 ds_read (B+A-lo, both kk); issue ALL 8 stages for tc+1
//   C0 (A-lo x kk0), C1 (A-lo x kk1)
//   [sched_barrier pin — keeps A-hi reads from hoisting (VGPR budget)]
//   8 ds_read (A-hi); C2, C3
//   ONE {vmcnt(0) + s_barrier} per tile — the drain is free because tc+1's
//   stages were issued a full tile (~5700 cyc >> 900 cyc HBM latency) ago.
// XOR chunk^row LDS swizzle (0 conflicts), XCD 4x4 block chunks, setprio.
// EPI: 0 = bf16 (+bias), 1 = bf16 gelu(+bias), 2 = residual +=
// HBF (EPI=2 only): 0 -> f32 h scatter, 1 -> bf16 h coalesced LDS-repack RMW
// ---------------------------------------------------------------------------
template <int EPI, int HBF>
__global__ __launch_bounds__(512, 2) void gemmp(
    const unsigned short* __restrict__ A, const unsigned short* __restrict__ Bt,
    const float* __restrict__ bias, unsigned short* __restrict__ Cb,
    void* __restrict__ Hres, int N, int K, int gx, int gy) {
  constexpr int A_E = 16384;               // 256x64 A elems
  constexpr int BUF_E = A_E + 16384;       // + B 256x64
  __shared__ alignas(16) unsigned short smem[2 * BUF_E];

  // ---- block swizzle: XCD contiguous range; 4x4 chunks, bx fastest ----
  const int nwg = gx * gy;
  const int dd = blockIdx.x;
  const int wrk = (dd & 7) * (nwg >> 3) + (dd >> 3);
  const int cid = wrk >> 4;
  const int cin = wrk & 15;
  const int cpr = gx >> 2;
  const int cby = cid / cpr;
  const int cbx = cid - cby * cpr;
  const int bx = cbx * 4 + (cin & 3);
  const int by = cby * 4 + (cin >> 2);
  const int row0 = by * 256, col0 = bx * 256;

  const int t = threadIdx.x;
  const int wid = t >> 6, l = t & 63;
  const int wm = wid >> 2, wn = wid & 3;
  const int fr = l & 15, q4 = l >> 4;

  const int cx0 = (q4 ^ (fr & 7)) * 8;
  const int cx1 = ((4 + q4) ^ (fr & 7)) * 8;
  const int b_r0 = (wn * 64 + fr) * 64;
  auto a_slot = [&](int m) -> int { return (wm * 128 + m * 16 + fr) * 64; };

  const int lrow = l >> 3;
  const int scol = ((l & 7) ^ (lrow & 7)) * 8;

  auto stB = [&](int tt, int win) {
    const unsigned short* s =
        Bt + (size_t)(col0 + win * 8 + lrow) * K + tt * 64 + scol;
    __builtin_amdgcn_global_load_lds(
        (const __attribute__((address_space(1))) void*)s,
        (__attribute__((address_space(3))) void*)(smem + (tt & 1) * BUF_E + A_E + win * 512),
        16, 0, 0);
  };
  auto stA = [&](int tt, int win) {
    const unsigned short* s =
        A + (size_t)(row0 + win * 8 + lrow) * K + tt * 64 + scol;
    __builtin_amdgcn_global_load_lds(
        (const __attribute__((address_space(1))) void*)s,
        (__attribute__((address_space(3))) void*)(smem + (tt & 1) * BUF_E + win * 512),
        16, 0, 0);
  };
  auto stage_all = [&](int tt) {     // 8 loads/thread: full next tile
    stB(tt, 2 * wid); stB(tt, 2 * wid + 1);
    stB(tt, 16 + 2 * wid); stB(tt, 16 + 2 * wid + 1);
    stA(tt, 2 * wid); stA(tt, 2 * wid + 1);
    stA(tt, 16 + 2 * wid); stA(tt, 16 + 2 * wid + 1);
  };

  const int nt = K >> 6;

  stage_all(0);
  SYNC_TILE();

  f32x4 acc[8][4];
#pragma unroll
  for (int m = 0; m < 8; ++m)
#pragma unroll
    for (int n = 0; n < 4; ++n) {
      acc[m][n].x = 0.f; acc[m][n].y = 0.f; acc[m][n].z = 0.f; acc[m][n].w = 0.f;
    }

  for (int tc = 0; tc < nt; ++tc) {
    const unsigned short* Ab = smem + (tc & 1) * BUF_E;
    const unsigned short* Bb = Ab + A_E;
    const bool pf = (tc + 1) < nt;

    // ---- tile-top reads: B both kk, A-lo both kk (16 x ds_read_b128) ----
    bf16x8 b0[4], b1[4], a0[4], a1[4];
#pragma unroll
    for (int n = 0; n < 4; ++n) b0[n] = *(const bf16x8*)(Bb + b_r0 + n * 1024 + cx0);
#pragma unroll
    for (int m = 0; m < 4; ++m) a0[m] = *(const bf16x8*)(Ab + a_slot(m) + cx0);
#pragma unroll
    for (int n = 0; n < 4; ++n) b1[n] = *(const bf16x8*)(Bb + b_r0 + n * 1024 + cx1);
#pragma unroll
    for (int m = 0; m < 4; ++m) a1[m] = *(const bf16x8*)(Ab + a_slot(m) + cx1);

    // ---- issue ALL of tile tc+1's staging (a full tile of latency cover) --
    if (pf) stage_all(tc + 1);

    // ---- C0: A-lo x kk0 ----
    __builtin_amdgcn_s_setprio(1);
#pragma unroll
    for (int m = 0; m < 4; ++m)
#pragma unroll
      for (int n = 0; n < 4; ++n)
        acc[m][n] = __builtin_amdgcn_mfma_f32_16x16x32_bf16(a0[m], b0[n], acc[m][n], 0, 0, 0);
    __builtin_amdgcn_s_setprio(0);

    // ---- C1: A-lo x kk1 ----
    __builtin_amdgcn_s_setprio(1);
#pragma unroll
    for (int m = 0; m < 4; ++m)
#pragma unroll
      for (int n = 0; n < 4; ++n)
        acc[m][n] = __builtin_amdgcn_mfma_f32_16x16x32_bf16(a1[m], b1[n], acc[m][n], 0, 0, 0);
    __builtin_amdgcn_s_setprio(0);

    // keep A-hi reads below C0/C1 (register-pressure pin; no wave sync)
    __builtin_amdgcn_sched_barrier(0);

    // ---- A-hi reads (8) then C2, C3 — no barrier in between ----
    bf16x8 h0[4], h1[4];
#pragma unroll
    for (int m = 0; m < 4; ++m) h0[m] = *(const bf16x8*)(Ab + a_slot(4 + m) + cx0);
#pragma unroll
    for (int m = 0; m < 4; ++m) h1[m] = *(const bf16x8*)(Ab + a_slot(4 + m) + cx1);

    __builtin_amdgcn_s_setprio(1);
#pragma unroll
    for (int m = 0; m < 4; ++m)
#pragma unroll
      for (int n = 0; n < 4; ++n)
        acc[4 + m][n] = __builtin_amdgcn_mfma_f32_16x16x32_bf16(h0[m], b0[n], acc[4 + m][n], 0, 0, 0);
    __builtin_amdgcn_s_setprio(0);
    __builtin_amdgcn_s_setprio(1);
#pragma unroll
    for (int m = 0; m < 4; ++m)
#pragma unroll
      for (int n = 0; n < 4; ++n)
        acc[4 + m][n] = __builtin_amdgcn_mfma_f32_16x16x32_bf16(h1[m], b1[n], acc[4 + m][n], 0, 0, 0);
    __builtin_amdgcn_s_setprio(0);

    // ---- ONE boundary sync per tile ----
    SYNC_TILE();
  }

  // ---- epilogue ----
  if constexpr (EPI == 2 && HBF == 0) {
    float* Hf = (float*)Hres;
#pragma unroll
    for (int n = 0; n < 4; ++n) {
      const int col = col0 + wn * 64 + n * 16 + fr;
      const float bi = bias[col];
#pragma unroll
      for (int m = 0; m < 8; ++m)
#pragma unroll
        for (int e = 0; e < 4; ++e) {
          const int row = row0 + wm * 128 + m * 16 + q4 * 4 + e;
          Hf[(size_t)row * N + col] += acc[m][n][e] + bi;
        }
    }
  } else {
    unsigned short* Hb = (unsigned short*)Hres;
    char* wreg = (char*)smem + wid * 9216;
    float bi[4];
#pragma unroll
    for (int n = 0; n < 4; ++n) bi[n] = bias[col0 + wn * 64 + n * 16 + fr];
#pragma unroll
    for (int half = 0; half < 2; ++half) {
#pragma unroll
      for (int m = 0; m < 4; ++m)
#pragma unroll
        for (int n = 0; n < 4; ++n)
#pragma unroll
          for (int e = 0; e < 4; ++e) {
            float v = acc[half * 4 + m][n][e] + bi[n];
            if (EPI == 1) v = gelu_new(v);
            *(unsigned short*)(wreg + (m * 16 + q4 * 4 + e) * 144 +
                               (n * 16 + fr) * 2) = f2bf(v);
          }
#pragma unroll
      for (int rb = 0; rb < 8; ++rb) {
        const int rowl = rb * 8 + (l >> 3);
        u16x8 vv = *(const u16x8*)(wreg + rowl * 144 + (l & 7) * 16);
        const int rg = row0 + wm * 128 + half * 64 + rowl;
        unsigned short* dst =
            (EPI == 2 ? Hb : Cb) + (size_t)rg * N + col0 + wn * 64 + (l & 7) * 8;
        if (EPI == 2) {
          u16x8 hv = *(const u16x8*)dst;
          u16x8 o;
#pragma unroll
          for (int e = 0; e < 8; ++e) o[e] = f2bf(b2f(hv[e]) + b2f(vv[e]));
          *(u16x8*)dst = o;
        } else {
          *(u16x8*)dst = vv;
        }
      }
    }
  }
}

// ---------------------------------------------------------------------------
// MFMA flash attention (unchanged; verified rounds 3-11).
// ---------------------------------------------------------------------------
__global__ __launch_bounds__(256) void attn_mfma(
    const unsigned short* __restrict__ qkv, unsigned short* __restrict__ aout,
    int b0) {
  __shared__ alignas(16) unsigned short Klds[256 * 64];
  __shared__ alignas(16) unsigned short Vt[64 * 256];
  const int bh = blockIdx.x;
  const int bl = bh >> 4, hd = bh & 15;
  const size_t base = (size_t)bl * 256 * 3072 + (size_t)hd * 64;
  const int t = threadIdx.x;
  const int w = t >> 6, l = t & 63;
  const int lq = l & 31, hl = l >> 5;

#pragma unroll
  for (int i = 0; i < 8; ++i) {
    const int r = i * 32 + (t >> 3);
    const int c = t & 7;
    u16x8 kv = *(const u16x8*)(qkv + base + (size_t)r * 3072 + 1024 + c * 8);
    *(u16x8*)(Klds + r * 64 + ((c ^ (r & 7)) * 8)) = kv;
    u16x8 vv = *(const u16x8*)(qkv + base + (size_t)r * 3072 + 2048 + c * 8);
#pragma unroll
    for (int j = 0; j < 8; ++j) {
      const int d = c * 8 + j;
      Vt[d * 256 + (((r >> 3) ^ (d & 31)) * 8) + (r & 7)] = vv[j];
    }
  }

  const int q0 = w * 64;
  bf16x8 qf[2][4];
#pragma unroll
  for (int n = 0; n < 2; ++n)
#pragma unroll
    for (int d16 = 0; d16 < 4; ++d16)
      qf[n][d16] = *(const bf16x8*)(qkv + base +
          (size_t)(q0 + n * 32 + lq) * 3072 + d16 * 16 + hl * 8);
  __syncthreads();

  const float cs = 0.125f * 1.44269504088896f;
  f32x16 O[2][2];
#pragma unroll
  for (int m = 0; m < 2; ++m)
#pragma unroll
    for (int n = 0; n < 2; ++n)
#pragma unroll
      for (int e = 0; e < 16; ++e) O[m][n][e] = 0.f;
  float mrun[2] = {-3.0e38f, -3.0e38f};
  float lrun[2] = {0.f, 0.f};

  const int ktmax = (q0 + 63) >> 5;
  for (int kt = 0; kt <= ktmax; ++kt) {
    bf16x8 kf[4];
    const int krow = kt * 32 + lq;
#pragma unroll
    for (int d16 = 0; d16 < 4; ++d16) {
      const int chunk = (d16 * 2 + hl) ^ (krow & 7);
      kf[d16] = *(const bf16x8*)(Klds + krow * 64 + chunk * 8);
    }
    const int nlo = (kt * 32 > q0 + 31) ? 1 : 0;
    bf16x8 pfrag[2][2];
#pragma unroll
    for (int n = 0; n < 2; ++n) {
      if (n < nlo) continue;
      f32x16 s;
#pragma unroll
      for (int e = 0; e < 16; ++e) s[e] = 0.f;
#pragma unroll
      for (int d16 = 0; d16 < 4; ++d16)
        s = __builtin_amdgcn_mfma_f32_32x32x16_bf16(kf[d16], qf[n][d16], s, 0, 0, 0);
      const int qg = q0 + n * 32 + lq;
      float sv[16];
#pragma unroll
      for (int r = 0; r < 16; ++r) {
        const int kg = kt * 32 + (r & 3) + 8 * (r >> 2) + 4 * hl;
        const float x = s[r] * cs;
        sv[r] = (kg > qg) ? -3.0e38f : x;
      }
      float pmax = sv[0];
#pragma unroll
      for (int r = 1; r < 16; ++r) pmax = fmaxf(pmax, sv[r]);
      pmax = fmaxf(pmax, __shfl_xor(pmax, 32, 64));
      const float nm = fmaxf(mrun[n], pmax);
      const float alpha = exp2f(mrun[n] - nm);
      mrun[n] = nm;
      float psum = 0.f;
#pragma unroll
      for (int r = 0; r < 16; ++r) {
        sv[r] = exp2f(sv[r] - nm);
        psum += sv[r];
      }
      psum += __shfl_xor(psum, 32, 64);
      lrun[n] = lrun[n] * alpha + psum;
#pragma unroll
      for (int m = 0; m < 2; ++m)
#pragma unroll
        for (int e = 0; e < 16; ++e) O[m][n][e] *= alpha;
#pragma unroll
      for (int h = 0; h < 2; ++h) {
        unsigned int a0 = cvtpk(sv[h * 8 + 0], sv[h * 8 + 1]);
        unsigned int a1 = cvtpk(sv[h * 8 + 2], sv[h * 8 + 3]);
        unsigned int c0 = cvtpk(sv[h * 8 + 4], sv[h * 8 + 5]);
        unsigned int c1 = cvtpk(sv[h * 8 + 6], sv[h * 8 + 7]);
        plswap(a0, c0);
        plswap(a1, c1);
        u32x4 fw; fw.x = a0; fw.y = a1; fw.z = c0; fw.w = c1;
        pfrag[n][h] = __builtin_bit_cast(bf16x8, fw);
      }
    }
#pragma unroll
    for (int m = 0; m < 2; ++m)
#pragma unroll
      for (int h = 0; h < 2; ++h) {
        const int dd = m * 32 + lq;
        const int chunk = (kt * 4 + h * 2 + hl) ^ (dd & 31);
        bf16x8 vf = *(const bf16x8*)(Vt + dd * 256 + chunk * 8);
#pragma unroll
        for (int n = 0; n < 2; ++n)
          if (n >= nlo)
            O[m][n] = __builtin_amdgcn_mfma_f32_32x32x16_bf16(vf, pfrag[n][h], O[m][n], 0, 0, 0);
      }
  }

#pragma unroll
  for (int n = 0; n < 2; ++n) {
    const float inv = 1.0f / lrun[n];
    const size_t row = (size_t)(b0 + bl) * 256 + q0 + n * 32 + lq;
#pragma unroll
    for (int m = 0; m < 2; ++m) {
#pragma unroll
      for (int qd = 0; qd < 4; ++qd) {
        u16x4 pk;
#pragma unroll
        for (int e = 0; e < 4; ++e) pk[e] = f2bf(O[m][n][qd * 4 + e] * inv);
        *(u16x4*)(aout + row * 1024 + hd * 64 + m * 32 + qd * 8 + hl * 4) = pk;
      }
    }
  }
}

// ---------------------------------------------------------------------------
// Loss
// ---------------------------------------------------------------------------
__device__ __forceinline__ float block_reduce_sum256(float v) {
#pragma unroll
  for (int off = 32; off; off >>= 1) v += __shfl_xor(v, off, 64);
  __shared__ float red[4];
  const int t = threadIdx.x;
  if ((t & 63) == 0) red[t >> 6] = v;
  __syncthreads();
  return red[0] + red[1] + red[2] + red[3];
}

__global__ __launch_bounds__(256) void loss_partial(
    const float* __restrict__ hf, const float* __restrict__ sent,
    float* __restrict__ part) {
  const int s = blockIdx.x, t = threadIdx.x;
  f32x4 a = ((const f32x4*)(hf + (size_t)s * 1024))[t];
  f32x4 b = ((const f32x4*)(sent + (size_t)(s + 1) * 1024))[t];
  f32x4 d = a - b;
  float v = d.x * d.x + d.y * d.y + d.z * d.z + d.w * d.w;
  float tot = block_reduce_sum256(v);
  if (t == 0) part[s] = tot;
}

__global__ __launch_bounds__(256) void loss_final(
    const float* __restrict__ part, float* __restrict__ out) {
  const int t = threadIdx.x;
  float v = (t < 255) ? part[t] : 0.f;
  float s = block_reduce_sum256(v);
  if (t == 0) out[0] = s * (1.0f / (255.0f * 1024.0f));
}

// ---------------------------------------------------------------------------
// Workspace layouts (identical to round 10)
// ---------------------------------------------------------------------------
constexpr size_t F_X     = 0;
constexpr size_t F_U     = 33554432;
constexpr size_t F_WQKV  = F_U + 134217728;
constexpr size_t F_WPROJ = F_WQKV + 6291456;
constexpr size_t F_WFC   = F_WPROJ + 2097152;
constexpr size_t F_WMLP  = F_WFC + 8388608;
constexpr size_t F_PART  = F_WMLP + 8388608;

constexpr size_t G_X     = 0;
constexpr size_t G_H     = 33554432;
constexpr size_t G_U     = G_H + 33554432;
constexpr size_t G_WQKV  = G_U + 134217728;
constexpr size_t G_WPROJ = G_WQKV + 6291456;
constexpr size_t G_WFC   = G_WPROJ + 2097152;
constexpr size_t G_WMLP  = G_WFC + 8388608;
constexpr size_t G_PART  = G_WMLP + 8388608;
constexpr size_t G_NEED  = G_PART + 4096;

extern "C" void kernel_launch(void* const* d_in, const int* in_sizes, int n_in,
                              void* d_out, int out_size, void* d_ws, size_t ws_size,
                              hipStream_t stream) {
  (void)in_sizes; (void)n_in; (void)out_size;
  const float* sent    = (const float*)d_in[0];
  const float* wpe     = (const float*)d_in[1];
  const float* ln1_g   = (const float*)d_in[2];
  const float* ln1_b   = (const float*)d_in[3];
  const float* attn_w  = (const float*)d_in[4];
  const float* attn_b  = (const float*)d_in[5];
  const float* attn_pw = (const float*)d_in[6];
  const float* attn_pb = (const float*)d_in[7];
  const float* ln2_g   = (const float*)d_in[8];
  const float* ln2_b   = (const float*)d_in[9];
  const float* fc_w    = (const float*)d_in[10];
  const float* fc_b    = (const float*)d_in[11];
  const float* mlp_w   = (const float*)d_in[12];
  const float* mlp_b   = (const float*)d_in[13];
  const float* lnf_g   = (const float*)d_in[14];
  const float* lnf_b   = (const float*)d_in[15];
  float* out_h = (float*)d_out;

  char* ws = (char*)d_ws;
  const bool t2 = ws_size >= G_NEED;

  unsigned short* xb    = (unsigned short*)(ws + (t2 ? G_X : F_X));
  unsigned short* hb    = (unsigned short*)(ws + G_H);
  unsigned short* ub    = (unsigned short*)(ws + (t2 ? G_U : F_U));
  unsigned short* wqkv  = (unsigned short*)(ws + (t2 ? G_WQKV : F_WQKV));
  unsigned short* wproj = (unsigned short*)(ws + (t2 ? G_WPROJ : F_WPROJ));
  unsigned short* wfc   = (unsigned short*)(ws + (t2 ? G_WFC : F_WFC));
  unsigned short* wmlp  = (unsigned short*)(ws + (t2 ? G_WMLP : F_WMLP));
  float* part           = (float*)(ws + (t2 ? G_PART : F_PART));

  void* h = t2 ? (void*)hb : (void*)out_h;

  const dim3 tb(32, 8, 1);
  for (int i = 0; i < 2; ++i) {
    transpose_bf16<<<dim3(96, 32), tb, 0, stream>>>(
        attn_w + (size_t)i * 1024 * 3072, wqkv, 1024, 3072);
    transpose_bf16<<<dim3(32, 32), tb, 0, stream>>>(
        attn_pw + (size_t)i * 1024 * 1024, wproj, 1024, 1024);
    transpose_bf16<<<dim3(128, 32), tb, 0, stream>>>(
        fc_w + (size_t)i * 1024 * 4096, wfc, 1024, 4096);
    transpose_bf16<<<dim3(32, 128), tb, 0, stream>>>(
        mlp_w + (size_t)i * 4096 * 1024, wmlp, 4096, 1024);

    // --- attention block ---
    if (i == 0) {
      if (t2) ln4_wpe_kernel<1><<<4096, 256, 0, stream>>>(sent, wpe, ln1_g, ln1_b, h, xb);
      else    ln4_wpe_kernel<0><<<4096, 256, 0, stream>>>(sent, wpe, ln1_g, ln1_b, h, xb);
    } else {
      if (t2) ln4_kernel<1, 0><<<4096, 256, 0, stream>>>(h, ln1_g + i * 1024, ln1_b + i * 1024, xb);
      else    ln4_kernel<0, 0><<<4096, 256, 0, stream>>>(h, ln1_g + i * 1024, ln1_b + i * 1024, xb);
    }

    gemmp<0, 0><<<768, 512, 0, stream>>>(
        xb, wqkv, attn_b + i * 3072, ub, nullptr, 3072, 1024, 12, 64);
    attn_mfma<<<1024, 256, 0, stream>>>(ub, xb, 0);

    if (t2)
      gemmp<2, 1><<<256, 512, 0, stream>>>(
          xb, wproj, attn_pb + i * 1024, nullptr, h, 1024, 1024, 4, 64);
    else
      gemmp<2, 0><<<256, 512, 0, stream>>>(
          xb, wproj, attn_pb + i * 1024, nullptr, h, 1024, 1024, 4, 64);

    // --- MLP block ---
    if (t2) ln4_kernel<1, 0><<<4096, 256, 0, stream>>>(h, ln2_g + i * 1024, ln2_b + i * 1024, xb);
    else    ln4_kernel<0, 0><<<4096, 256, 0, stream>>>(h, ln2_g + i * 1024, ln2_b + i * 1024, xb);

    gemmp<1, 0><<<1024, 512, 0, stream>>>(
        xb, wfc, fc_b + i * 4096, ub, nullptr, 4096, 1024, 16, 64);

    if (t2)
      gemmp<2, 1><<<256, 512, 0, stream>>>(
          ub, wmlp, mlp_b + i * 1024, nullptr, h, 1024, 4096, 4, 64);
    else
      gemmp<2, 0><<<256, 512, 0, stream>>>(
          ub, wmlp, mlp_b + i * 1024, nullptr, h, 1024, 4096, 4, 64);
  }

  if (t2) ln4_kernel<1, 1><<<4096, 256, 0, stream>>>(h, lnf_g, lnf_b, out_h);
  else    ln4_kernel<0, 1><<<4096, 256, 0, stream>>>(h, lnf_g, lnf_b, out_h);
  loss_partial<<<255, 256, 0, stream>>>(out_h, sent, part);
  loss_final<<<1, 256, 0, stream>>>(part, out_h + 16777216);
}